// Round 1
// baseline (317.634 us; speedup 1.0000x reference)
//
#include <hip/hip_runtime.h>
#include <cstdint>

#define D 128
#define P 8
#define L 3

typedef __attribute__((ext_vector_type(8))) _Float16 f16x8;
typedef __attribute__((ext_vector_type(4))) float    f32x4;

// One pass over the edge list:
//  - epk[i] = (col << 15) | f16bits(val)   (val in [0,1) -> sign bit 0, lossless f16)
//  - row_ptr via adjacent-difference on the sorted edge_row (O(E), no binary search)
__global__ void prep_edges(const int* __restrict__ er, const int* __restrict__ col,
                           const float* __restrict__ vals,
                           int* __restrict__ rp, uint32_t* __restrict__ epk,
                           int n, int e) {
    int i = blockIdx.x * blockDim.x + threadIdx.x;
    if (i >= e) return;
    union { _Float16 h; uint16_t u; } v;
    v.h = (_Float16)vals[i];
    epk[i] = ((uint32_t)col[i] << 15) | (uint32_t)(v.u & 0x7FFFu);

    int cur = er[i];
    if (i == 0) {
        for (int r = 0; r <= cur; r++) rp[r] = 0;
    } else {
        int prev = er[i - 1];
        for (int r = prev + 1; r <= cur; r++) rp[r] = i;
    }
    if (i == e - 1) {
        for (int r = cur + 1; r <= n; r++) rp[r] = e;
    }
}

// ww = softmax-contracted weights, fp16, MFMA B-fragment layout:
// wwB[l][kt][o][k']  (i = kt*32 + k'); b-frag load is 16B contiguous.
__global__ void build_ww(const float* __restrict__ sp, const float* __restrict__ lw,
                         _Float16* __restrict__ wwB) {
    int idx = blockIdx.x * blockDim.x + threadIdx.x;
    if (idx >= L * D * D) return;
    int l = idx / (D * D);
    int rem = idx - l * D * D;
    int o = rem / D;
    int i = rem - o * D;
    float wv[P];
    float m = -1e30f;
#pragma unroll
    for (int p = 0; p < P; p++) { wv[p] = lw[l * P + p]; m = fmaxf(m, wv[p]); }
    float s = 0.f;
#pragma unroll
    for (int p = 0; p < P; p++) { wv[p] = __expf(wv[p] - m); s += wv[p]; }
    float inv = 1.0f / s;
    const float* spp = sp + ((size_t)(l * D + o) * D + i) * P;
    float acc = 0.f;
#pragma unroll
    for (int p = 0; p < P; p++) acc += spp[p] * wv[p];
    int kt = i >> 5, kp = i & 31;
    wwB[(((l * 4 + kt) * D + o) << 5) + kp] = (_Float16)(acc * inv);
}

// MFMA on a 16x128 staged tile: 8 output col-tiles split 2-per-wave.
// All 4 waves read the same 16 rows (LDS broadcast).
static __device__ __forceinline__ void mfma_store16(const _Float16 (*s_h)[136],
                                                    const _Float16* __restrict__ wwB_l,
                                                    _Float16* __restrict__ y,
                                                    int row0, int n, int tid) {
    const int w = tid >> 6, lane = tid & 63;
    const int quad = lane >> 4, l16 = lane & 15;
    f32x4 acc[2] = {};
#pragma unroll
    for (int kt = 0; kt < 4; kt++) {
        f16x8 af = *(const f16x8*)&s_h[l16][kt * 32 + quad * 8];
#pragma unroll
        for (int c = 0; c < 2; c++) {
            const int ct = w * 2 + c;
            f16x8 bf = *(const f16x8*)&wwB_l[((kt * D + ct * 16 + l16) << 5) + quad * 8];
            acc[c] = __builtin_amdgcn_mfma_f32_16x16x32_f16(af, bf, acc[c], 0, 0, 0);
        }
    }
    // C/D layout: col = lane&15, row = quad*4 + reg (m89-verified)
#pragma unroll
    for (int c = 0; c < 2; c++) {
        const int ct = w * 2 + c;
#pragma unroll
        for (int rg = 0; rg < 4; rg++) {
            int row = row0 + quad * 4 + rg;
            if (row < n) y[row * D + ct * 16 + l16] = (_Float16)acc[c][rg];
        }
    }
}

// Y1 = cast_f16(x) * W0   (x fp32 read directly; cast fused). 16-row tiles.
__global__ __launch_bounds__(256, 8)
void gemm_x32(const float* __restrict__ x, const _Float16* __restrict__ wwB_l,
              _Float16* __restrict__ y, int n) {
    __shared__ _Float16 s_h[16][136];
    const int tid = threadIdx.x;
    const int row0 = blockIdx.x * 16;
    const int c8 = (tid & 15) * 8;
    {
        int r = tid >> 4;              // 0..15, one row per subgroup
        int row = row0 + r;
        float4 v0 = {}, v1 = {};
        if (row < n) {
            v0 = *(const float4*)&x[row * D + c8];
            v1 = *(const float4*)&x[row * D + c8 + 4];
        }
        f16x8 h;
        h[0] = (_Float16)v0.x; h[1] = (_Float16)v0.y;
        h[2] = (_Float16)v0.z; h[3] = (_Float16)v0.w;
        h[4] = (_Float16)v1.x; h[5] = (_Float16)v1.y;
        h[6] = (_Float16)v1.z; h[7] = (_Float16)v1.w;
        *(f16x8*)&s_h[r][c8] = h;
    }
    __syncthreads();
    mfma_store16(s_h, wwB_l, y, row0, n, tid);
}

// ---------------- wave-per-row gather core ----------------
// Whole wave (64 lanes) processes one destination row; lane covers 2 of the
// 128 columns (4 B gather per lane). Edge meta (packed u32) and row bounds are
// wave-uniform -> scalar loads; NB-deep chunk keeps NB gathers in flight.
template<int NB>
static __device__ __forceinline__ void gather_chunk(float& a0, float& a1,
                                                    const _Float16* __restrict__ y,
                                                    const uint32_t* __restrict__ epk,
                                                    int e, int l2) {
    uint32_t m[NB];
#pragma unroll
    for (int j = 0; j < NB; j++) m[j] = epk[e + j];   // uniform -> s_load
    uint32_t g[NB];
#pragma unroll
    for (int j = 0; j < NB; j++) {
        uint32_t off = (m[j] >> 15) * (uint32_t)D + (uint32_t)l2;
        g[j] = *(const uint32_t*)&y[off];             // 256 B per wave instr
    }
#pragma unroll
    for (int j = 0; j < NB; j++) {
        union { uint32_t u; _Float16 h[2]; } gg; gg.u = g[j];
        union { uint16_t u; _Float16 h; } vv; vv.u = (uint16_t)(m[j] & 0x7FFFu);
        float vf = (float)vv.h;                       // fp16 edge weight
        a0 += vf * (float)gg.h[0];                    // v_fma_mix_f32
        a1 += vf * (float)gg.h[1];
    }
}

static __device__ __forceinline__ void gather_row64(float& a0, float& a1,
                                                    const _Float16* __restrict__ y,
                                                    const uint32_t* __restrict__ epk,
                                                    int e, int e1, int l2) {
    for (; e + 16 <= e1; e += 16) gather_chunk<16>(a0, a1, y, epk, e, l2);
    if (e + 8 <= e1) { gather_chunk<8>(a0, a1, y, epk, e, l2); e += 8; }
    if (e + 4 <= e1) { gather_chunk<4>(a0, a1, y, epk, e, l2); e += 4; }
    for (; e < e1; e++) gather_chunk<1>(a0, a1, y, epk, e, l2);
}

// Fused layer: Y_next = relu(adj * Y_prev) * W.  16-row tiles; each of the 4
// waves serially owns 4 rows (balance: sum of 4 Poisson(16) per wave).
__global__ __launch_bounds__(256, 8)
void fused_layer(const _Float16* __restrict__ yprev, const int* __restrict__ rp,
                 const uint32_t* __restrict__ epk, const _Float16* __restrict__ wwB_l,
                 _Float16* __restrict__ ynext, int n) {
    __shared__ _Float16 s_h[16][136];
    const int tid = threadIdx.x;
    const int lane = tid & 63;
    const int l2 = lane * 2;
    const int w = __builtin_amdgcn_readfirstlane(tid >> 6);
    const int row0 = blockIdx.x * 16;
    const int rbase = row0 + w * 4;
#pragma unroll 1
    for (int q = 0; q < 4; q++) {
        const int r = rbase + q;
        float a0 = 0.f, a1 = 0.f;
        if (r < n) {
            int e  = __builtin_amdgcn_readfirstlane(rp[r]);
            int e1 = __builtin_amdgcn_readfirstlane(rp[r + 1]);
            gather_row64(a0, a1, yprev, epk, e, e1, l2);
        }
        union { uint32_t u; _Float16 h[2]; } o;
        o.h[0] = (_Float16)fmaxf(a0, 0.f);
        o.h[1] = (_Float16)fmaxf(a1, 0.f);
        *(uint32_t*)&s_h[w * 4 + q][l2] = o.u;        // 2-way bank alias: free
    }
    __syncthreads();
    mfma_store16(s_h, wwB_l, ynext, row0, n, tid);
}

// Final: out = adj * Y3, fp32 out. No LDS, float2 stores.
__global__ __launch_bounds__(256, 8)
void spmm_f32(const _Float16* __restrict__ y, const int* __restrict__ rp,
              const uint32_t* __restrict__ epk, float* __restrict__ out, int n) {
    const int tid = threadIdx.x;
    const int lane = tid & 63;
    const int l2 = lane * 2;
    const int w = __builtin_amdgcn_readfirstlane(tid >> 6);
    const int rbase = blockIdx.x * 16 + w * 4;
#pragma unroll 1
    for (int q = 0; q < 4; q++) {
        const int r = rbase + q;
        if (r >= n) continue;
        float a0 = 0.f, a1 = 0.f;
        int e  = __builtin_amdgcn_readfirstlane(rp[r]);
        int e1 = __builtin_amdgcn_readfirstlane(rp[r + 1]);
        gather_row64(a0, a1, y, epk, e, e1, l2);
        *(float2*)&out[(size_t)r * D + l2] = make_float2(a0, a1);
    }
}

extern "C" void kernel_launch(void* const* d_in, const int* in_sizes, int n_in,
                              void* d_out, int out_size, void* d_ws, size_t ws_size,
                              hipStream_t stream) {
    const int*   edge_row  = (const int*)d_in[0];
    const int*   edge_col  = (const int*)d_in[1];
    const float* edge_vals = (const float*)d_in[2];
    const float* x         = (const float*)d_in[3];
    const float* sp        = (const float*)d_in[4];
    const float* lw        = (const float*)d_in[5];
    float* out = (float*)d_out;

    const int E_ = in_sizes[0];
    const int N_ = in_sizes[3] / D;

    // Workspace: row_ptr | epk (packed edges) | wwB | bufA (N*D f16) | bufB
    // total ~ 0.4 + 6.4 + 0.1 + 25.6 + 25.6 = ~58.1 MB
    char* ws = (char*)d_ws;
    int* row_ptr = (int*)ws;
    size_t off = (((size_t)(N_ + 1) * sizeof(int)) + 255) & ~(size_t)255;
    uint32_t* epk = (uint32_t*)(ws + off);
    off += (size_t)E_ * sizeof(uint32_t);
    off = (off + 255) & ~(size_t)255;
    _Float16* wwB = (_Float16*)(ws + off);
    off += (size_t)L * 4 * D * 32 * sizeof(_Float16);
    off = (off + 255) & ~(size_t)255;
    _Float16* bufA = (_Float16*)(ws + off);
    off += (size_t)N_ * D * sizeof(_Float16);
    _Float16* bufB = (_Float16*)(ws + off);

    prep_edges<<<(E_ + 255) / 256, 256, 0, stream>>>(edge_row, edge_col, edge_vals,
                                                     row_ptr, epk, N_, E_);
    build_ww<<<(L * D * D + 255) / 256, 256, 0, stream>>>(sp, lw, wwB);

    const int sblk = (N_ + 15) / 16;
    const int WWL = 4 * D * 32;   // per-layer wwB stride

    // Y1 = x*W0 ; Y2 = relu(adj*Y1)*W1 ; Y3 = relu(adj*Y2)*W2 ; out = adj*Y3
    gemm_x32<<<sblk, 256, 0, stream>>>(x, wwB, bufA, N_);
    fused_layer<<<sblk, 256, 0, stream>>>(bufA, row_ptr, epk, wwB + WWL,     bufB, N_);
    fused_layer<<<sblk, 256, 0, stream>>>(bufB, row_ptr, epk, wwB + 2 * WWL, bufA, N_);
    spmm_f32<<<sblk, 256, 0, stream>>>(bufA, row_ptr, epk, out, N_);
}

// Round 2
// 295.905 us; speedup vs baseline: 1.0734x; 1.0734x over previous
//
#include <hip/hip_runtime.h>
#include <cstdint>

#define D 128
#define P 8
#define L 3

typedef __attribute__((ext_vector_type(8))) _Float16 f16x8;
typedef __attribute__((ext_vector_type(4))) float    f32x4;
typedef __attribute__((ext_vector_type(2))) float    f32x2;

#if __has_builtin(__builtin_amdgcn_cvt_pk_f32_fp8) && __has_builtin(__builtin_amdgcn_cvt_pk_fp8_f32)
#define HAVE_FP8_CVT 1
#else
#define HAVE_FP8_CVT 0
#endif

// ---- fp8 e4m3fn <-> f32 (OCP, gfx950) ----
static __device__ __forceinline__ f32x2 fp8x2_to_f32(uint32_t u) {
#if HAVE_FP8_CVT
    return __builtin_amdgcn_cvt_pk_f32_fp8((int)u, false);
#else
    f32x2 r;
#pragma unroll
    for (int i = 0; i < 2; i++) {
        uint32_t b = (u >> (8 * i)) & 0xffu;
        uint32_t mag = b & 0x7fu;
        // e4m3 -> f16 bits: exp+8, mant<<7; denormals -> 0 (negligible at per-row scale)
        uint16_t h = (uint16_t)(((b & 0x80u) << 8) | ((mag >= 8u) ? ((mag << 7) + 0x2000u) : 0u));
        union { uint16_t q; _Float16 hf; } c; c.q = h;
        r[i] = (float)c.hf;
    }
    return r;
#endif
}

static __device__ __forceinline__ uint32_t f32_to_fp8(float v) {
    // caller pre-clamps to [-448, 448]
#if HAVE_FP8_CVT
    return (uint32_t)__builtin_amdgcn_cvt_pk_fp8_f32(v, v, 0, false) & 0xffu;
#else
    union { _Float16 hf; uint16_t q; } c; c.hf = (_Float16)v;
    uint32_t s = ((uint32_t)c.q >> 8) & 0x80u;
    int t = (int)(c.q & 0x7fff) - 0x2000;   // rebias exp (15 -> 7), keep m10
    if (t < 0) return s;                    // below 2^-6: flush (denormal range)
    int r = (t + 63 + ((t >> 7) & 1)) >> 7; // RNE on dropped 7 bits
    if (r > 0x7e) r = 0x7e;                 // 0x7f is NaN in e4m3fn
    return s | (uint32_t)r;
#endif
}

// One pass over the edge list:
//  - epk[i] = (col << 15) | f16bits(val)   (val in [0,1) -> sign bit 0, lossless f16)
//  - row_ptr via adjacent-difference on the sorted edge_row (O(E), no binary search)
__global__ void prep_edges(const int* __restrict__ er, const int* __restrict__ col,
                           const float* __restrict__ vals,
                           int* __restrict__ rp, uint32_t* __restrict__ epk,
                           int n, int e) {
    int i = blockIdx.x * blockDim.x + threadIdx.x;
    if (i >= e) return;
    union { _Float16 h; uint16_t u; } v;
    v.h = (_Float16)vals[i];
    epk[i] = ((uint32_t)col[i] << 15) | (uint32_t)(v.u & 0x7FFFu);

    int cur = er[i];
    if (i == 0) {
        for (int r = 0; r <= cur; r++) rp[r] = 0;
    } else {
        int prev = er[i - 1];
        for (int r = prev + 1; r <= cur; r++) rp[r] = i;
    }
    if (i == e - 1) {
        for (int r = cur + 1; r <= n; r++) rp[r] = e;
    }
}

// ww = softmax-contracted weights, fp16, MFMA B-fragment layout:
// wwB[l][kt][o][k']  (i = kt*32 + k'); b-frag load is 16B contiguous.
__global__ void build_ww(const float* __restrict__ sp, const float* __restrict__ lw,
                         _Float16* __restrict__ wwB) {
    int idx = blockIdx.x * blockDim.x + threadIdx.x;
    if (idx >= L * D * D) return;
    int l = idx / (D * D);
    int rem = idx - l * D * D;
    int o = rem / D;
    int i = rem - o * D;
    float wv[P];
    float m = -1e30f;
#pragma unroll
    for (int p = 0; p < P; p++) { wv[p] = lw[l * P + p]; m = fmaxf(m, wv[p]); }
    float s = 0.f;
#pragma unroll
    for (int p = 0; p < P; p++) { wv[p] = __expf(wv[p] - m); s += wv[p]; }
    float inv = 1.0f / s;
    const float* spp = sp + ((size_t)(l * D + o) * D + i) * P;
    float acc = 0.f;
#pragma unroll
    for (int p = 0; p < P; p++) acc += spp[p] * wv[p];
    int kt = i >> 5, kp = i & 31;
    wwB[(((l * 4 + kt) * D + o) << 5) + kp] = (_Float16)(acc * inv);
}

// MFMA on a 16x128 staged tile; quantize output to fp8 e4m3 with per-row scale.
// srow: LDS[16] pre-zeroed by caller before its __syncthreads().
static __device__ __forceinline__ void mfma_store16_q8(const _Float16 (*s_h)[136],
                                                       const _Float16* __restrict__ wwB_l,
                                                       uint8_t* __restrict__ y8,
                                                       float* __restrict__ scl,
                                                       unsigned* srow,
                                                       int row0, int n, int tid) {
    const int w = tid >> 6, lane = tid & 63;
    const int quad = lane >> 4, l16 = lane & 15;
    f32x4 acc[2] = {};
#pragma unroll
    for (int kt = 0; kt < 4; kt++) {
        f16x8 af = *(const f16x8*)&s_h[l16][kt * 32 + quad * 8];
#pragma unroll
        for (int c = 0; c < 2; c++) {
            const int ct = w * 2 + c;
            f16x8 bf = *(const f16x8*)&wwB_l[((kt * D + ct * 16 + l16) << 5) + quad * 8];
            acc[c] = __builtin_amdgcn_mfma_f32_16x16x32_f16(af, bf, acc[c], 0, 0, 0);
        }
    }
    // C/D layout: col = lane&15, row = quad*4 + reg (m89-verified).
    // Row quad*4+rg lives in the 16 lanes of this quad -> 16-lane shuffle max,
    // then cross-wave LDS atomicMax (uint compare valid: values >= 0).
#pragma unroll
    for (int rg = 0; rg < 4; rg++) {
        float m = fmaxf(fabsf(acc[0][rg]), fabsf(acc[1][rg]));
#pragma unroll
        for (int d = 1; d < 16; d <<= 1) m = fmaxf(m, __shfl_xor(m, d));
        if (l16 == 0) atomicMax(&srow[quad * 4 + rg], __float_as_uint(m));
    }
    __syncthreads();
#pragma unroll
    for (int rg = 0; rg < 4; rg++) {
        const int rr = quad * 4 + rg;
        const int row = row0 + rr;
        float rmax = fmaxf(__uint_as_float(srow[rr]), 1e-20f);
        float qs = 448.f / rmax;
        if (row < n) {
#pragma unroll
            for (int c = 0; c < 2; c++) {
                const int ct = w * 2 + c;
                float v = acc[c][rg] * qs;
                v = fminf(fmaxf(v, -448.f), 448.f);
                y8[row * D + ct * 16 + l16] = (uint8_t)f32_to_fp8(v);
            }
            if (w == 0 && l16 == 0) scl[row] = rmax * (1.f / 448.f);
        }
    }
}

// Y1 = cast_f16(x) * W0, quantized to fp8 + per-row scale.
__global__ __launch_bounds__(256, 8)
void gemm_x32(const float* __restrict__ x, const _Float16* __restrict__ wwB_l,
              uint8_t* __restrict__ y8, float* __restrict__ scl, int n) {
    __shared__ _Float16 s_h[16][136];
    __shared__ unsigned srow[16];
    const int tid = threadIdx.x;
    const int row0 = blockIdx.x * 16;
    const int c8 = (tid & 15) * 8;
    if (tid < 16) srow[tid] = 0;
    {
        int r = tid >> 4;              // 0..15, one row per subgroup
        int row = row0 + r;
        float4 v0 = {}, v1 = {};
        if (row < n) {
            v0 = *(const float4*)&x[row * D + c8];
            v1 = *(const float4*)&x[row * D + c8 + 4];
        }
        f16x8 h;
        h[0] = (_Float16)v0.x; h[1] = (_Float16)v0.y;
        h[2] = (_Float16)v0.z; h[3] = (_Float16)v0.w;
        h[4] = (_Float16)v1.x; h[5] = (_Float16)v1.y;
        h[6] = (_Float16)v1.z; h[7] = (_Float16)v1.w;
        *(f16x8*)&s_h[r][c8] = h;
    }
    __syncthreads();
    mfma_store16_q8(s_h, wwB_l, y8, scl, srow, row0, n, tid);
}

// ---------------- wave-per-row fp8 gather core ----------------
// Whole wave processes one destination row; lane covers 2 of 128 cols (2 B).
// Edge meta, row bounds and per-source-row scale are wave-uniform -> scalar loads.
template<int NB>
static __device__ __forceinline__ void gather_chunk(float& a0, float& a1,
                                                    const uint8_t* __restrict__ y8,
                                                    const uint32_t* __restrict__ epk,
                                                    const float* __restrict__ scl,
                                                    int e, int l2) {
    uint32_t m[NB];
#pragma unroll
    for (int j = 0; j < NB; j++) m[j] = epk[e + j];       // uniform -> s_load
    float sc[NB];
#pragma unroll
    for (int j = 0; j < NB; j++) sc[j] = scl[m[j] >> 15]; // uniform -> s_load (L2-resident 400KB)
    uint32_t g[NB];
#pragma unroll
    for (int j = 0; j < NB; j++)
        g[j] = *(const uint16_t*)&y8[(m[j] >> 15) * (uint32_t)D + (uint32_t)l2]; // 128 B/wave
#pragma unroll
    for (int j = 0; j < NB; j++) {
        union { uint16_t u; _Float16 h; } vv; vv.u = (uint16_t)(m[j] & 0x7FFFu);
        float vf = (float)vv.h * sc[j];                   // edge weight * row dequant scale
        f32x2 p = fp8x2_to_f32(g[j]);
        a0 += vf * p[0];
        a1 += vf * p[1];
    }
}

static __device__ __forceinline__ void gather_row64(float& a0, float& a1,
                                                    const uint8_t* __restrict__ y8,
                                                    const uint32_t* __restrict__ epk,
                                                    const float* __restrict__ scl,
                                                    int e, int e1, int l2) {
    for (; e + 16 <= e1; e += 16) gather_chunk<16>(a0, a1, y8, epk, scl, e, l2);
    if (e + 8 <= e1) { gather_chunk<8>(a0, a1, y8, epk, scl, e, l2); e += 8; }
    if (e + 4 <= e1) { gather_chunk<4>(a0, a1, y8, epk, scl, e, l2); e += 4; }
    for (; e < e1; e++) gather_chunk<1>(a0, a1, y8, epk, scl, e, l2);
}

// Fused layer: Y_next = q8( relu(adj * deq(Y_prev)) * W ).  16-row tiles.
__global__ __launch_bounds__(256, 8)
void fused_layer(const uint8_t* __restrict__ yprev, const float* __restrict__ sprev,
                 const int* __restrict__ rp, const uint32_t* __restrict__ epk,
                 const _Float16* __restrict__ wwB_l,
                 uint8_t* __restrict__ ynext, float* __restrict__ snext, int n) {
    __shared__ _Float16 s_h[16][136];
    __shared__ unsigned srow[16];
    const int tid = threadIdx.x;
    const int lane = tid & 63;
    const int l2 = lane * 2;
    const int w = __builtin_amdgcn_readfirstlane(tid >> 6);
    const int row0 = blockIdx.x * 16;
    const int rbase = row0 + w * 4;
    if (tid < 16) srow[tid] = 0;
#pragma unroll 1
    for (int q = 0; q < 4; q++) {
        const int r = rbase + q;
        float a0 = 0.f, a1 = 0.f;
        if (r < n) {
            int e  = __builtin_amdgcn_readfirstlane(rp[r]);
            int e1 = __builtin_amdgcn_readfirstlane(rp[r + 1]);
            gather_row64(a0, a1, yprev, epk, sprev, e, e1, l2);
        }
        union { uint32_t u; _Float16 h[2]; } o;
        o.h[0] = (_Float16)fmaxf(a0, 0.f);
        o.h[1] = (_Float16)fmaxf(a1, 0.f);
        *(uint32_t*)&s_h[w * 4 + q][l2] = o.u;        // 2-way bank alias: free
    }
    __syncthreads();
    mfma_store16_q8(s_h, wwB_l, ynext, snext, srow, row0, n, tid);
}

// Final: out = adj * deq(Y3), fp32 out. No LDS, float2 stores.
__global__ __launch_bounds__(256, 8)
void spmm_f32(const uint8_t* __restrict__ y8, const float* __restrict__ sprev,
              const int* __restrict__ rp, const uint32_t* __restrict__ epk,
              float* __restrict__ out, int n) {
    const int tid = threadIdx.x;
    const int lane = tid & 63;
    const int l2 = lane * 2;
    const int w = __builtin_amdgcn_readfirstlane(tid >> 6);
    const int rbase = blockIdx.x * 16 + w * 4;
#pragma unroll 1
    for (int q = 0; q < 4; q++) {
        const int r = rbase + q;
        if (r >= n) continue;
        float a0 = 0.f, a1 = 0.f;
        int e  = __builtin_amdgcn_readfirstlane(rp[r]);
        int e1 = __builtin_amdgcn_readfirstlane(rp[r + 1]);
        gather_row64(a0, a1, y8, epk, sprev, e, e1, l2);
        *(float2*)&out[(size_t)r * D + l2] = make_float2(a0, a1);
    }
}

extern "C" void kernel_launch(void* const* d_in, const int* in_sizes, int n_in,
                              void* d_out, int out_size, void* d_ws, size_t ws_size,
                              hipStream_t stream) {
    const int*   edge_row  = (const int*)d_in[0];
    const int*   edge_col  = (const int*)d_in[1];
    const float* edge_vals = (const float*)d_in[2];
    const float* x         = (const float*)d_in[3];
    const float* sp        = (const float*)d_in[4];
    const float* lw        = (const float*)d_in[5];
    float* out = (float*)d_out;

    const int E_ = in_sizes[0];
    const int N_ = in_sizes[3] / D;

    // Workspace: row_ptr | epk | wwB | y8A | y8B | scA | scB   (~33 MB)
    char* ws = (char*)d_ws;
    int* row_ptr = (int*)ws;
    size_t off = (((size_t)(N_ + 1) * sizeof(int)) + 255) & ~(size_t)255;
    uint32_t* epk = (uint32_t*)(ws + off);
    off += (size_t)E_ * sizeof(uint32_t);
    off = (off + 255) & ~(size_t)255;
    _Float16* wwB = (_Float16*)(ws + off);
    off += (size_t)L * 4 * D * 32 * sizeof(_Float16);
    off = (off + 255) & ~(size_t)255;
    uint8_t* y8A = (uint8_t*)(ws + off);
    off += (size_t)N_ * D;
    uint8_t* y8B = (uint8_t*)(ws + off);
    off += (size_t)N_ * D;
    off = (off + 255) & ~(size_t)255;
    float* scA = (float*)(ws + off);
    off += (size_t)N_ * sizeof(float);
    float* scB = (float*)(ws + off);

    prep_edges<<<(E_ + 255) / 256, 256, 0, stream>>>(edge_row, edge_col, edge_vals,
                                                     row_ptr, epk, N_, E_);
    build_ww<<<(L * D * D + 255) / 256, 256, 0, stream>>>(sp, lw, wwB);

    const int sblk = (N_ + 15) / 16;
    const int WWL = 4 * D * 32;   // per-layer wwB stride

    // Y1 = x*W0 ; Y2 = relu(adj*Y1)*W1 ; Y3 = relu(adj*Y2)*W2 ; out = adj*Y3
    gemm_x32<<<sblk, 256, 0, stream>>>(x, wwB, y8A, scA, N_);
    fused_layer<<<sblk, 256, 0, stream>>>(y8A, scA, row_ptr, epk, wwB + WWL,     y8B, scB, N_);
    fused_layer<<<sblk, 256, 0, stream>>>(y8B, scB, row_ptr, epk, wwB + 2 * WWL, y8A, scA, N_);
    spmm_f32<<<sblk, 256, 0, stream>>>(y8A, scA, row_ptr, epk, out, N_);
}

// Round 4
// 266.658 us; speedup vs baseline: 1.1912x; 1.1097x over previous
//
#include <hip/hip_runtime.h>
#include <cstdint>

#define D 128
#define P 8
#define L 3

typedef __attribute__((ext_vector_type(8))) _Float16 f16x8;
typedef __attribute__((ext_vector_type(4))) float    f32x4;
typedef __attribute__((ext_vector_type(2))) float    f32x2;

#if __has_builtin(__builtin_amdgcn_cvt_pk_f32_fp8) && __has_builtin(__builtin_amdgcn_cvt_pk_fp8_f32)
#define HAVE_FP8_CVT 1
#else
#define HAVE_FP8_CVT 0
#endif

// ---- fp8 e4m3fn -> f32 pair (OCP, gfx950). HI selects bytes 2,3 of u.
// NOTE: the builtin's word-select is an instruction immediate -> template param.
template<bool HI>
static __device__ __forceinline__ f32x2 fp8_pair(uint32_t u) {
#if HAVE_FP8_CVT
    return __builtin_amdgcn_cvt_pk_f32_fp8((int)u, HI);
#else
    uint32_t w = HI ? (u >> 16) : u;
    f32x2 r;
#pragma unroll
    for (int i = 0; i < 2; i++) {
        uint32_t b = (w >> (8 * i)) & 0xffu;
        uint32_t mag = b & 0x7fu;
        uint16_t h = (uint16_t)(((b & 0x80u) << 8) | ((mag >= 8u) ? ((mag << 7) + 0x2000u) : 0u));
        union { uint16_t q; _Float16 hf; } c; c.q = h;
        r[i] = (float)c.hf;
    }
    return r;
#endif
}

static __device__ __forceinline__ uint32_t f32_to_fp8(float v) {
    // caller pre-clamps to [-448, 448]
#if HAVE_FP8_CVT
    return (uint32_t)__builtin_amdgcn_cvt_pk_fp8_f32(v, v, 0, false) & 0xffu;
#else
    union { _Float16 hf; uint16_t q; } c; c.hf = (_Float16)v;
    uint32_t s = ((uint32_t)c.q >> 8) & 0x80u;
    int t = (int)(c.q & 0x7fff) - 0x2000;   // rebias exp (15 -> 7), keep m10
    if (t < 0) return s;                    // below 2^-6: flush (denormal range)
    int r = (t + 63 + ((t >> 7) & 1)) >> 7; // RNE on dropped 7 bits
    if (r > 0x7e) r = 0x7e;                 // 0x7f is NaN in e4m3fn
    return s | (uint32_t)r;
#endif
}

// One pass over the edge list:
//  - epk[i] = (col << 15) | f16bits(val)   (val in [0,1) -> sign bit 0, lossless f16)
//  - row_ptr via adjacent-difference on the sorted edge_row (O(E), no binary search)
__global__ void prep_edges(const int* __restrict__ er, const int* __restrict__ col,
                           const float* __restrict__ vals,
                           int* __restrict__ rp, uint32_t* __restrict__ epk,
                           int n, int e) {
    int i = blockIdx.x * blockDim.x + threadIdx.x;
    if (i >= e) return;
    union { _Float16 h; uint16_t u; } v;
    v.h = (_Float16)vals[i];
    epk[i] = ((uint32_t)col[i] << 15) | (uint32_t)(v.u & 0x7FFFu);

    int cur = er[i];
    if (i == 0) {
        for (int r = 0; r <= cur; r++) rp[r] = 0;
    } else {
        int prev = er[i - 1];
        for (int r = prev + 1; r <= cur; r++) rp[r] = i;
    }
    if (i == e - 1) {
        for (int r = cur + 1; r <= n; r++) rp[r] = e;
    }
}

// ww = softmax-contracted weights, fp16, MFMA B-fragment layout:
// wwB[l][kt][o][k']  (i = kt*32 + k'); b-frag load is 16B contiguous.
__global__ void build_ww(const float* __restrict__ sp, const float* __restrict__ lw,
                         _Float16* __restrict__ wwB) {
    int idx = blockIdx.x * blockDim.x + threadIdx.x;
    if (idx >= L * D * D) return;
    int l = idx / (D * D);
    int rem = idx - l * D * D;
    int o = rem / D;
    int i = rem - o * D;
    float wv[P];
    float m = -1e30f;
#pragma unroll
    for (int p = 0; p < P; p++) { wv[p] = lw[l * P + p]; m = fmaxf(m, wv[p]); }
    float s = 0.f;
#pragma unroll
    for (int p = 0; p < P; p++) { wv[p] = __expf(wv[p] - m); s += wv[p]; }
    float inv = 1.0f / s;
    const float* spp = sp + ((size_t)(l * D + o) * D + i) * P;
    float acc = 0.f;
#pragma unroll
    for (int p = 0; p < P; p++) acc += spp[p] * wv[p];
    int kt = i >> 5, kp = i & 31;
    wwB[(((l * 4 + kt) * D + o) << 5) + kp] = (_Float16)(acc * inv);
}

// MFMA on a 16x128 staged tile; quantize output to fp8 e4m3 with per-row scale.
// srow: LDS[16] pre-zeroed by caller before its __syncthreads().
static __device__ __forceinline__ void mfma_store16_q8(const _Float16 (*s_h)[136],
                                                       const _Float16* __restrict__ wwB_l,
                                                       uint8_t* __restrict__ y8,
                                                       float* __restrict__ scl,
                                                       unsigned* srow,
                                                       int row0, int n, int tid) {
    const int w = tid >> 6, lane = tid & 63;
    const int quad = lane >> 4, l16 = lane & 15;
    f32x4 acc[2] = {};
#pragma unroll
    for (int kt = 0; kt < 4; kt++) {
        f16x8 af = *(const f16x8*)&s_h[l16][kt * 32 + quad * 8];
#pragma unroll
        for (int c = 0; c < 2; c++) {
            const int ct = w * 2 + c;
            f16x8 bf = *(const f16x8*)&wwB_l[((kt * D + ct * 16 + l16) << 5) + quad * 8];
            acc[c] = __builtin_amdgcn_mfma_f32_16x16x32_f16(af, bf, acc[c], 0, 0, 0);
        }
    }
    // C/D layout: col = lane&15, row = quad*4 + reg (m89-verified).
    // Row max: 16-lane shuffle max within quad, cross-wave LDS atomicMax (uint ok: >=0).
#pragma unroll
    for (int rg = 0; rg < 4; rg++) {
        float m = fmaxf(fabsf(acc[0][rg]), fabsf(acc[1][rg]));
#pragma unroll
        for (int d = 1; d < 16; d <<= 1) m = fmaxf(m, __shfl_xor(m, d));
        if (l16 == 0) atomicMax(&srow[quad * 4 + rg], __float_as_uint(m));
    }
    __syncthreads();
#pragma unroll
    for (int rg = 0; rg < 4; rg++) {
        const int rr = quad * 4 + rg;
        const int row = row0 + rr;
        float rmax = fmaxf(__uint_as_float(srow[rr]), 1e-20f);
        float qs = 448.f / rmax;
        if (row < n) {
#pragma unroll
            for (int c = 0; c < 2; c++) {
                const int ct = w * 2 + c;
                float v = acc[c][rg] * qs;
                v = fminf(fmaxf(v, -448.f), 448.f);
                y8[row * D + ct * 16 + l16] = (uint8_t)f32_to_fp8(v);
            }
            if (w == 0 && l16 == 0) scl[row] = rmax * (1.f / 448.f);
        }
    }
}

// Y1 = cast_f16(x) * W0, quantized to fp8 + per-row scale.
__global__ __launch_bounds__(256, 8)
void gemm_x32(const float* __restrict__ x, const _Float16* __restrict__ wwB_l,
              uint8_t* __restrict__ y8, float* __restrict__ scl, int n) {
    __shared__ _Float16 s_h[16][136];
    __shared__ unsigned srow[16];
    const int tid = threadIdx.x;
    const int row0 = blockIdx.x * 16;
    const int c8 = (tid & 15) * 8;
    if (tid < 16) srow[tid] = 0;
    {
        int r = tid >> 4;              // 0..15, one row per subgroup
        int row = row0 + r;
        float4 v0 = {}, v1 = {};
        if (row < n) {
            v0 = *(const float4*)&x[row * D + c8];
            v1 = *(const float4*)&x[row * D + c8 + 4];
        }
        f16x8 h;
        h[0] = (_Float16)v0.x; h[1] = (_Float16)v0.y;
        h[2] = (_Float16)v0.z; h[3] = (_Float16)v0.w;
        h[4] = (_Float16)v1.x; h[5] = (_Float16)v1.y;
        h[6] = (_Float16)v1.z; h[7] = (_Float16)v1.w;
        *(f16x8*)&s_h[r][c8] = h;
    }
    __syncthreads();
    mfma_store16_q8(s_h, wwB_l, y8, scl, srow, row0, n, tid);
}

// ---------------- subgroup-per-row fp8 gather core (high-MLP) ----------------
// 16 lanes per row; lane covers 8 of 128 cols (8 B gather). 4 rows run
// CONCURRENTLY per wave (independent accumulators -> deep load pipelining).
template<int NB>
static __device__ __forceinline__ void gather_chunk8(float (&a)[8],
                                                     const uint8_t* __restrict__ y8,
                                                     const uint32_t* __restrict__ epk,
                                                     const float* __restrict__ scl,
                                                     int e, int c8) {
    uint32_t m[NB];
#pragma unroll
    for (int j = 0; j < NB; j++) m[j] = epk[e + j];     // subgroup-broadcast load
    uint2 g[NB]; float sc[NB];
#pragma unroll
    for (int j = 0; j < NB; j++) {
        uint32_t row = m[j] >> 15;
        g[j]  = *(const uint2*)&y8[row * (uint32_t)D + (uint32_t)c8];  // 8 fp8
        sc[j] = scl[row];                               // L2-resident 400 KB
    }
#pragma unroll
    for (int j = 0; j < NB; j++) {
        union { uint16_t u; _Float16 h; } vv; vv.u = (uint16_t)(m[j] & 0x7FFFu);
        float vf = (float)vv.h * sc[j];                 // edge weight * dequant scale
        f32x2 p;
        p = fp8_pair<false>(g[j].x); a[0] += vf * p[0]; a[1] += vf * p[1];
        p = fp8_pair<true >(g[j].x); a[2] += vf * p[0]; a[3] += vf * p[1];
        p = fp8_pair<false>(g[j].y); a[4] += vf * p[0]; a[5] += vf * p[1];
        p = fp8_pair<true >(g[j].y); a[6] += vf * p[0]; a[7] += vf * p[1];
    }
}

static __device__ __forceinline__ void gather_row8(float (&a)[8],
                                                   const uint8_t* __restrict__ y8,
                                                   const uint32_t* __restrict__ epk,
                                                   const float* __restrict__ scl,
                                                   int e, int e1, int c8) {
    for (; e + 8 <= e1; e += 8) gather_chunk8<8>(a, y8, epk, scl, e, c8);
    if (e + 4 <= e1) { gather_chunk8<4>(a, y8, epk, scl, e, c8); e += 4; }
    for (; e < e1; e++) gather_chunk8<1>(a, y8, epk, scl, e, c8);
}

// Fused layer: Y_next = q8( relu(adj * deq(Y_prev)) * W ).  16-row tiles,
// one 16-lane subgroup per row (4 concurrent rows per wave).
__global__ __launch_bounds__(256, 6)
void fused_layer(const uint8_t* __restrict__ yprev, const float* __restrict__ sprev,
                 const int* __restrict__ rp, const uint32_t* __restrict__ epk,
                 const _Float16* __restrict__ wwB_l,
                 uint8_t* __restrict__ ynext, float* __restrict__ snext, int n) {
    __shared__ _Float16 s_h[16][136];
    __shared__ unsigned srow[16];
    const int tid = threadIdx.x;
    const int row0 = blockIdx.x * 16;
    const int sg = tid >> 4;          // 0..15, one row per subgroup
    const int c8 = (tid & 15) * 8;
    if (tid < 16) srow[tid] = 0;
    {
        int r = row0 + sg;
        float a[8] = {0.f, 0.f, 0.f, 0.f, 0.f, 0.f, 0.f, 0.f};
        if (r < n) gather_row8(a, yprev, epk, sprev, rp[r], rp[r + 1], c8);
        f16x8 o;
#pragma unroll
        for (int k = 0; k < 8; k++) o[k] = (_Float16)fmaxf(a[k], 0.f);
        *(f16x8*)&s_h[sg][c8] = o;
    }
    __syncthreads();
    mfma_store16_q8(s_h, wwB_l, ynext, snext, srow, row0, n, tid);
}

// Final: out = adj * deq(Y3), fp32 out. No LDS, float4 stores.
__global__ __launch_bounds__(256, 6)
void spmm_f32(const uint8_t* __restrict__ y8, const float* __restrict__ sprev,
              const int* __restrict__ rp, const uint32_t* __restrict__ epk,
              float* __restrict__ out, int n) {
    const int tid = threadIdx.x;
    const int r = blockIdx.x * 16 + (tid >> 4);
    const int c8 = (tid & 15) * 8;
    if (r >= n) return;
    float a[8] = {0.f, 0.f, 0.f, 0.f, 0.f, 0.f, 0.f, 0.f};
    gather_row8(a, y8, epk, sprev, rp[r], rp[r + 1], c8);
    *(float4*)&out[(size_t)r * D + c8]     = make_float4(a[0], a[1], a[2], a[3]);
    *(float4*)&out[(size_t)r * D + c8 + 4] = make_float4(a[4], a[5], a[6], a[7]);
}

extern "C" void kernel_launch(void* const* d_in, const int* in_sizes, int n_in,
                              void* d_out, int out_size, void* d_ws, size_t ws_size,
                              hipStream_t stream) {
    const int*   edge_row  = (const int*)d_in[0];
    const int*   edge_col  = (const int*)d_in[1];
    const float* edge_vals = (const float*)d_in[2];
    const float* x         = (const float*)d_in[3];
    const float* sp        = (const float*)d_in[4];
    const float* lw        = (const float*)d_in[5];
    float* out = (float*)d_out;

    const int E_ = in_sizes[0];
    const int N_ = in_sizes[3] / D;

    // Workspace: row_ptr | epk | wwB | y8A | y8B | scA | scB   (~33 MB)
    char* ws = (char*)d_ws;
    int* row_ptr = (int*)ws;
    size_t off = (((size_t)(N_ + 1) * sizeof(int)) + 255) & ~(size_t)255;
    uint32_t* epk = (uint32_t*)(ws + off);
    off += (size_t)E_ * sizeof(uint32_t);
    off = (off + 255) & ~(size_t)255;
    _Float16* wwB = (_Float16*)(ws + off);
    off += (size_t)L * 4 * D * 32 * sizeof(_Float16);
    off = (off + 255) & ~(size_t)255;
    uint8_t* y8A = (uint8_t*)(ws + off);
    off += (size_t)N_ * D;
    uint8_t* y8B = (uint8_t*)(ws + off);
    off += (size_t)N_ * D;
    off = (off + 255) & ~(size_t)255;
    float* scA = (float*)(ws + off);
    off += (size_t)N_ * sizeof(float);
    float* scB = (float*)(ws + off);

    prep_edges<<<(E_ + 255) / 256, 256, 0, stream>>>(edge_row, edge_col, edge_vals,
                                                     row_ptr, epk, N_, E_);
    build_ww<<<(L * D * D + 255) / 256, 256, 0, stream>>>(sp, lw, wwB);

    const int sblk = (N_ + 15) / 16;
    const int WWL = 4 * D * 32;   // per-layer wwB stride

    // Y1 = x*W0 ; Y2 = relu(adj*Y1)*W1 ; Y3 = relu(adj*Y2)*W2 ; out = adj*Y3
    gemm_x32<<<sblk, 256, 0, stream>>>(x, wwB, y8A, scA, N_);
    fused_layer<<<sblk, 256, 0, stream>>>(y8A, scA, row_ptr, epk, wwB + WWL,     y8B, scB, N_);
    fused_layer<<<sblk, 256, 0, stream>>>(y8B, scB, row_ptr, epk, wwB + 2 * WWL, y8A, scA, N_);
    spmm_f32<<<sblk, 256, 0, stream>>>(y8A, scA, row_ptr, epk, out, N_);
}